// Round 1
// baseline (406.556 us; speedup 1.0000x reference)
//
#include <hip/hip_runtime.h>

#define EMBED 1024
#define NH 16
#define HD 64
#define SEQ 2048
#define BATCH 2
#define ROWS (BATCH*SEQ)   // 4096
#define BHD (BATCH*NH)     // 32

typedef __bf16 bf16x8 __attribute__((ext_vector_type(8)));
typedef float f32x4 __attribute__((ext_vector_type(4)));

__device__ __forceinline__ unsigned short f2bf(float f){
  union { float f; unsigned u; } v; v.f = f;
  unsigned r = v.u + 0x7fffu + ((v.u >> 16) & 1u);
  return (unsigned short)(r >> 16);
}
__device__ __forceinline__ float bf2f(unsigned short s){
  union { unsigned u; float f; } v; v.u = ((unsigned)s) << 16; return v.f;
}

// ---------------- prep kernels ----------------

__global__ __launch_bounds__(256) void k_conv(const float* __restrict__ x,
                                              unsigned short* __restrict__ xb, int n4){
  int i = blockIdx.x * blockDim.x + threadIdx.x;
  if (i < n4){
    float4 f = ((const float4*)x)[i];
    ushort4 o;
    o.x = f2bf(f.x); o.y = f2bf(f.y); o.z = f2bf(f.z); o.w = f2bf(f.w);
    ((ushort4*)xb)[i] = o;
  }
}

// in[R][C] fp32 -> out[C][R] bf16
__global__ __launch_bounds__(256) void k_tr_f2b(const float* __restrict__ in,
                                                unsigned short* __restrict__ out, int R, int C){
  __shared__ float t[32][33];
  int c0 = blockIdx.x * 32, r0 = blockIdx.y * 32;
  int tx = threadIdx.x, ty = threadIdx.y;
  #pragma unroll
  for (int i = 0; i < 4; i++){ int r = ty + i*8; t[r][tx] = in[(size_t)(r0+r)*C + c0 + tx]; }
  __syncthreads();
  #pragma unroll
  for (int i = 0; i < 4; i++){ int rr = ty + i*8; out[(size_t)(c0+rr)*R + r0 + tx] = f2bf(t[tx][rr]); }
}

// batched bf16 transpose: in[batch][R][C] -> out[batch][C][R]
__global__ __launch_bounds__(256) void k_tr_b2b(const unsigned short* __restrict__ in,
                                                unsigned short* __restrict__ out, int R, int C){
  in  += (size_t)blockIdx.z * R * C;
  out += (size_t)blockIdx.z * R * C;
  __shared__ unsigned short t[32][33];
  int c0 = blockIdx.x * 32, r0 = blockIdx.y * 32;
  int tx = threadIdx.x, ty = threadIdx.y;
  #pragma unroll
  for (int i = 0; i < 4; i++){ int r = ty + i*8; t[r][tx] = in[(size_t)(r0+r)*C + c0 + tx]; }
  __syncthreads();
  #pragma unroll
  for (int i = 0; i < 4; i++){ int rr = ty + i*8; out[(size_t)(c0+rr)*R + r0 + tx] = t[tx][rr]; }
}

// qn/kn from bf16-rounded q,k (keeps denominator = |q~ - k~|^2 >= 0)
__global__ __launch_bounds__(256) void k_norms(const unsigned short* __restrict__ q,
                                               const unsigned short* __restrict__ k,
                                               float* __restrict__ qn, float* __restrict__ kn){
  int i = blockIdx.x * blockDim.x + threadIdx.x;  // [0, 65536)
  const uint4* qr = (const uint4*)(q + (size_t)i * HD);
  const uint4* kr = (const uint4*)(k + (size_t)i * HD);
  float sq = 0.f, sk = 0.f;
  #pragma unroll
  for (int t = 0; t < 8; t++){
    uint4 uq = qr[t], uk = kr[t];
    unsigned aq[4] = {uq.x, uq.y, uq.z, uq.w};
    unsigned ak[4] = {uk.x, uk.y, uk.z, uk.w};
    #pragma unroll
    for (int j = 0; j < 4; j++){
      float f0 = bf2f((unsigned short)(aq[j] & 0xffff));
      float f1 = bf2f((unsigned short)(aq[j] >> 16));
      sq += f0*f0 + f1*f1;
      float g0 = bf2f((unsigned short)(ak[j] & 0xffff));
      float g1 = bf2f((unsigned short)(ak[j] >> 16));
      sk += g0*g0 + g1*g1;
    }
  }
  qn[i] = sq; kn[i] = sk;
}

// ---------------- GEMM1: x @ w_qkv + b -> scatter q,k,v [BH][L][D] bf16 ----------------

__global__ __launch_bounds__(256) void k_gemm_qkv(
    const unsigned short* __restrict__ A,    // [4096][1024] bf16
    const unsigned short* __restrict__ BT,   // [3072][1024] bf16
    const float* __restrict__ bias,          // [3072]
    unsigned short* __restrict__ qo, unsigned short* __restrict__ ko,
    unsigned short* __restrict__ vo)
{
  __shared__ __align__(16) unsigned short As[64][32];
  __shared__ __align__(16) unsigned short Bs[64][32];
  const int K = EMBED;
  int m0 = blockIdx.x * 64, n0 = blockIdx.y * 64;
  int tid = threadIdx.x, lane = tid & 63, wave = tid >> 6;
  int wm = wave >> 1, wn = wave & 1;
  int l16 = lane & 15, quad = lane >> 4;
  f32x4 acc[2][2] = {};
  int lr = tid >> 2, lc = (tid & 3) * 8;
  for (int k0 = 0; k0 < K; k0 += 32){
    *(uint4*)&As[lr][lc] = *(const uint4*)&A[(size_t)(m0 + lr) * K + k0 + lc];
    *(uint4*)&Bs[lr][lc] = *(const uint4*)&BT[(size_t)(n0 + lr) * K + k0 + lc];
    __syncthreads();
    bf16x8 af[2], bfr[2];
    #pragma unroll
    for (int mi = 0; mi < 2; mi++) af[mi]  = *(const bf16x8*)&As[wm*32 + mi*16 + l16][quad*8];
    #pragma unroll
    for (int ni = 0; ni < 2; ni++) bfr[ni] = *(const bf16x8*)&Bs[wn*32 + ni*16 + l16][quad*8];
    #pragma unroll
    for (int mi = 0; mi < 2; mi++)
      #pragma unroll
      for (int ni = 0; ni < 2; ni++)
        acc[mi][ni] = __builtin_amdgcn_mfma_f32_16x16x32_bf16(af[mi], bfr[ni], acc[mi][ni], 0, 0, 0);
    __syncthreads();
  }
  #pragma unroll
  for (int mi = 0; mi < 2; mi++)
    #pragma unroll
    for (int ni = 0; ni < 2; ni++)
      #pragma unroll
      for (int rr = 0; rr < 4; rr++){
        int row = m0 + wm*32 + mi*16 + quad*4 + rr;
        int col = n0 + wn*32 + ni*16 + l16;
        float val = acc[mi][ni][rr] + bias[col];
        int b = row >> 11, l = row & 2047;
        int which = col >> 10, e = col & 1023, h = e >> 6, d = e & 63;
        unsigned short* dst = which == 0 ? qo : (which == 1 ? ko : vo);
        dst[(((size_t)(b*NH + h))*SEQ + l)*HD + d] = f2bf(val);
      }
}

// ---------------- attention ----------------

__global__ __launch_bounds__(256) void k_attn(
    const unsigned short* __restrict__ qg,   // [BH][L][D]
    const unsigned short* __restrict__ kg,   // [BH][L][D]
    const unsigned short* __restrict__ vtg,  // [BH][D][L]
    const float* __restrict__ qn,
    const float* __restrict__ kn,
    unsigned short* __restrict__ attn_out)   // [ROWS][EMBED] bf16
{
  __shared__ __align__(16) unsigned short Pbuf[4][16][32];
  int bh = blockIdx.y; int b = bh >> 4, h = bh & 15;
  int tid = threadIdx.x, lane = tid & 63, wave = tid >> 6;
  int l16 = lane & 15, quad = lane >> 4;
  int q0 = blockIdx.x * 64 + wave * 16;
  const unsigned short* qbase = qg  + (size_t)bh * SEQ * HD;
  const unsigned short* kbase = kg  + (size_t)bh * SEQ * HD;
  const unsigned short* vtb   = vtg + (size_t)bh * HD * SEQ;
  const float* knb = kn + (size_t)bh * SEQ;

  bf16x8 aq[2];
  #pragma unroll
  for (int s = 0; s < 2; s++)
    aq[s] = *(const bf16x8*)&qbase[(size_t)(q0 + l16)*HD + s*32 + quad*8];
  float qn4[4];
  #pragma unroll
  for (int rr = 0; rr < 4; rr++) qn4[rr] = qn[(size_t)bh*SEQ + q0 + quad*4 + rr];

  float m_run[4], l_run[4];
  f32x4 oacc[4] = {};
  #pragma unroll
  for (int rr = 0; rr < 4; rr++){ m_run[rr] = -1e30f; l_run[rr] = 0.f; }

  unsigned short* pb = &Pbuf[wave][0][0];
  int jmax = q0 + 16;
  for (int j0 = 0; j0 < jmax; j0 += 32){
    f32x4 s[2] = {};
    #pragma unroll
    for (int half = 0; half < 2; half++)
      #pragma unroll
      for (int sk = 0; sk < 2; sk++){
        bf16x8 bk = *(const bf16x8*)&kbase[(size_t)(j0 + half*16 + l16)*HD + sk*32 + quad*8];
        s[half] = __builtin_amdgcn_mfma_f32_16x16x32_bf16(aq[sk], bk, s[half], 0, 0, 0);
      }
    float kn2[2] = { knb[j0 + l16], knb[j0 + 16 + l16] };
    float sc[2][4];
    #pragma unroll
    for (int half = 0; half < 2; half++)
      #pragma unroll
      for (int rr = 0; rr < 4; rr++){
        int jg = j0 + half*16 + l16;
        int mg = q0 + quad*4 + rr;
        float dot = s[half][rr];
        float den = fmaxf(qn4[rr] + kn2[half] - 2.0f*dot, 0.0f) + 1e-6f;
        float v = dot*dot/den;
        sc[half][rr] = (jg <= mg) ? v : -1e30f;
      }
    float alpha[4];
    #pragma unroll
    for (int rr = 0; rr < 4; rr++){
      float mx = fmaxf(sc[0][rr], sc[1][rr]);
      #pragma unroll
      for (int d = 1; d < 16; d <<= 1) mx = fmaxf(mx, __shfl_xor(mx, d));
      float mn = fmaxf(m_run[rr], mx);
      alpha[rr] = __expf(m_run[rr] - mn);
      m_run[rr] = mn;
    }
    #pragma unroll
    for (int rr = 0; rr < 4; rr++){
      float p0 = __expf(sc[0][rr] - m_run[rr]);
      float p1 = __expf(sc[1][rr] - m_run[rr]);
      sc[0][rr] = p0; sc[1][rr] = p1;
      float ps = p0 + p1;
      #pragma unroll
      for (int d = 1; d < 16; d <<= 1) ps += __shfl_xor(ps, d);
      l_run[rr] = l_run[rr]*alpha[rr] + ps;
    }
    #pragma unroll
    for (int g = 0; g < 4; g++)
      #pragma unroll
      for (int rr = 0; rr < 4; rr++) oacc[g][rr] *= alpha[rr];
    // P: C-layout -> LDS -> A-layout (bf16)
    #pragma unroll
    for (int half = 0; half < 2; half++)
      #pragma unroll
      for (int rr = 0; rr < 4; rr++)
        pb[(quad*4 + rr)*32 + half*16 + l16] = f2bf(sc[half][rr]);
    __asm__ volatile("" ::: "memory");
    __builtin_amdgcn_s_waitcnt(0xc07f);  // lgkmcnt(0)
    __asm__ volatile("" ::: "memory");
    bf16x8 ap = *(const bf16x8*)&pb[l16*32 + quad*8];
    #pragma unroll
    for (int g = 0; g < 4; g++){
      bf16x8 bv = *(const bf16x8*)&vtb[(size_t)(g*16 + l16)*SEQ + j0 + quad*8];
      oacc[g] = __builtin_amdgcn_mfma_f32_16x16x32_bf16(ap, bv, oacc[g], 0, 0, 0);
    }
  }
  #pragma unroll
  for (int g = 0; g < 4; g++)
    #pragma unroll
    for (int rr = 0; rr < 4; rr++){
      int lq = q0 + quad*4 + rr;
      int arow = b*SEQ + lq;
      int acol = h*HD + g*16 + l16;
      attn_out[(size_t)arow*EMBED + acol] = f2bf(oacc[g][rr] / l_run[rr]);
    }
}

// ---------------- GEMM2: attn_out @ w_out + b_out -> fp32 ----------------

__global__ __launch_bounds__(256) void k_gemm_out(
    const unsigned short* __restrict__ A,    // [4096][1024] bf16
    const unsigned short* __restrict__ BT,   // [1024][1024] bf16
    const float* __restrict__ bias,          // [1024]
    float* __restrict__ out)
{
  __shared__ __align__(16) unsigned short As[64][32];
  __shared__ __align__(16) unsigned short Bs[64][32];
  const int K = EMBED;
  int m0 = blockIdx.x * 64, n0 = blockIdx.y * 64;
  int tid = threadIdx.x, lane = tid & 63, wave = tid >> 6;
  int wm = wave >> 1, wn = wave & 1;
  int l16 = lane & 15, quad = lane >> 4;
  f32x4 acc[2][2] = {};
  int lr = tid >> 2, lc = (tid & 3) * 8;
  for (int k0 = 0; k0 < K; k0 += 32){
    *(uint4*)&As[lr][lc] = *(const uint4*)&A[(size_t)(m0 + lr) * K + k0 + lc];
    *(uint4*)&Bs[lr][lc] = *(const uint4*)&BT[(size_t)(n0 + lr) * K + k0 + lc];
    __syncthreads();
    bf16x8 af[2], bfr[2];
    #pragma unroll
    for (int mi = 0; mi < 2; mi++) af[mi]  = *(const bf16x8*)&As[wm*32 + mi*16 + l16][quad*8];
    #pragma unroll
    for (int ni = 0; ni < 2; ni++) bfr[ni] = *(const bf16x8*)&Bs[wn*32 + ni*16 + l16][quad*8];
    #pragma unroll
    for (int mi = 0; mi < 2; mi++)
      #pragma unroll
      for (int ni = 0; ni < 2; ni++)
        acc[mi][ni] = __builtin_amdgcn_mfma_f32_16x16x32_bf16(af[mi], bfr[ni], acc[mi][ni], 0, 0, 0);
    __syncthreads();
  }
  #pragma unroll
  for (int mi = 0; mi < 2; mi++)
    #pragma unroll
    for (int ni = 0; ni < 2; ni++)
      #pragma unroll
      for (int rr = 0; rr < 4; rr++){
        int row = m0 + wm*32 + mi*16 + quad*4 + rr;
        int col = n0 + wn*32 + ni*16 + l16;
        out[(size_t)row*EMBED + col] = acc[mi][ni][rr] + bias[col];
      }
}

// ---------------- launch ----------------

extern "C" void kernel_launch(void* const* d_in, const int* in_sizes, int n_in,
                              void* d_out, int out_size, void* d_ws, size_t ws_size,
                              hipStream_t stream) {
  const float* x     = (const float*)d_in[0];
  const float* w_qkv = (const float*)d_in[1];
  const float* b_qkv = (const float*)d_in[2];
  const float* w_out = (const float*)d_in[3];
  const float* b_out = (const float*)d_in[4];
  float* out = (float*)d_out;

  char* ws = (char*)d_ws;
  size_t off = 0;
  auto alloc = [&](size_t bytes) -> void* {
    void* p = ws + off; off += (bytes + 255) & ~(size_t)255; return p;
  };
  unsigned short* xb    = (unsigned short*)alloc((size_t)ROWS * EMBED * 2);      // 8 MB
  unsigned short* wqkvT = (unsigned short*)alloc((size_t)3 * EMBED * EMBED * 2); // 6 MB
  unsigned short* woutT = (unsigned short*)alloc((size_t)EMBED * EMBED * 2);     // 2 MB
  unsigned short* qb    = (unsigned short*)alloc((size_t)ROWS * EMBED * 2);
  unsigned short* kb    = (unsigned short*)alloc((size_t)ROWS * EMBED * 2);
  unsigned short* vb    = (unsigned short*)alloc((size_t)ROWS * EMBED * 2);
  unsigned short* vTb   = (unsigned short*)alloc((size_t)ROWS * EMBED * 2);
  float* qn = (float*)alloc((size_t)BHD * SEQ * 4);
  float* kn = (float*)alloc((size_t)BHD * SEQ * 4);
  unsigned short* attnb = xb;  // xb is dead after GEMM1 — alias to save workspace

  k_conv<<<dim3((ROWS*EMBED/4 + 255)/256), dim3(256), 0, stream>>>(x, xb, ROWS*EMBED/4);
  k_tr_f2b<<<dim3(3*EMBED/32, EMBED/32), dim3(32, 8), 0, stream>>>(w_qkv, wqkvT, EMBED, 3*EMBED);
  k_tr_f2b<<<dim3(EMBED/32, EMBED/32), dim3(32, 8), 0, stream>>>(w_out, woutT, EMBED, EMBED);
  k_gemm_qkv<<<dim3(ROWS/64, 3*EMBED/64), dim3(256), 0, stream>>>(xb, wqkvT, b_qkv, qb, kb, vb);
  k_norms<<<dim3(BHD*SEQ/256), dim3(256), 0, stream>>>(qb, kb, qn, kn);
  k_tr_b2b<<<dim3(HD/32, SEQ/32, BHD), dim3(32, 8), 0, stream>>>(vb, vTb, SEQ, HD);
  k_attn<<<dim3(SEQ/64, BHD), dim3(256), 0, stream>>>(qb, kb, vTb, qn, kn, attnb);
  k_gemm_out<<<dim3(ROWS/64, EMBED/64), dim3(256), 0, stream>>>(attnb, woutT, b_out, out);
}

// Round 2
// 353.740 us; speedup vs baseline: 1.1493x; 1.1493x over previous
//
#include <hip/hip_runtime.h>

#define EMBED 1024
#define NH 16
#define HD 64
#define SEQ 2048
#define BATCH 2
#define ROWS (BATCH*SEQ)   // 4096
#define BHD (BATCH*NH)     // 32

typedef __bf16 bf16x8 __attribute__((ext_vector_type(8)));
typedef _Float16 f16x4 __attribute__((ext_vector_type(4)));
typedef float f32x4 __attribute__((ext_vector_type(4)));

__device__ __forceinline__ unsigned short f2bf(float f){
  union { float f; unsigned u; } v; v.f = f;
  unsigned r = v.u + 0x7fffu + ((v.u >> 16) & 1u);
  return (unsigned short)(r >> 16);
}
__device__ __forceinline__ float bf2f(unsigned short s){
  union { unsigned u; float f; } v; v.u = ((unsigned)s) << 16; return v.f;
}
__device__ __forceinline__ unsigned short f2h(float f){
  union { _Float16 h; unsigned short u; } v; v.h = (_Float16)f; return v.u;
}

// ---------------- prep kernels ----------------

__global__ __launch_bounds__(256) void k_conv(const float* __restrict__ x,
                                              unsigned short* __restrict__ xb, int n4){
  int i = blockIdx.x * blockDim.x + threadIdx.x;
  if (i < n4){
    float4 f = ((const float4*)x)[i];
    ushort4 o;
    o.x = f2bf(f.x); o.y = f2bf(f.y); o.z = f2bf(f.z); o.w = f2bf(f.w);
    ((ushort4*)xb)[i] = o;
  }
}

// in[R][C] fp32 -> out[C][R] bf16
__global__ __launch_bounds__(256) void k_tr_f2b(const float* __restrict__ in,
                                                unsigned short* __restrict__ out, int R, int C){
  __shared__ float t[32][33];
  int c0 = blockIdx.x * 32, r0 = blockIdx.y * 32;
  int tx = threadIdx.x, ty = threadIdx.y;
  #pragma unroll
  for (int i = 0; i < 4; i++){ int r = ty + i*8; t[r][tx] = in[(size_t)(r0+r)*C + c0 + tx]; }
  __syncthreads();
  #pragma unroll
  for (int i = 0; i < 4; i++){ int rr = ty + i*8; out[(size_t)(c0+rr)*R + r0 + tx] = f2bf(t[tx][rr]); }
}

// batched 16-bit transpose: in[batch][R][C] -> out[batch][C][R]
__global__ __launch_bounds__(256) void k_tr_b2b(const unsigned short* __restrict__ in,
                                                unsigned short* __restrict__ out, int R, int C){
  in  += (size_t)blockIdx.z * R * C;
  out += (size_t)blockIdx.z * R * C;
  __shared__ unsigned short t[32][33];
  int c0 = blockIdx.x * 32, r0 = blockIdx.y * 32;
  int tx = threadIdx.x, ty = threadIdx.y;
  #pragma unroll
  for (int i = 0; i < 4; i++){ int r = ty + i*8; t[r][tx] = in[(size_t)(r0+r)*C + c0 + tx]; }
  __syncthreads();
  #pragma unroll
  for (int i = 0; i < 4; i++){ int rr = ty + i*8; out[(size_t)(c0+rr)*R + r0 + tx] = t[tx][rr]; }
}

// qn/kn from bf16-rounded q,k (keeps denominator = |q~ - k~|^2 >= 0)
__global__ __launch_bounds__(256) void k_norms(const unsigned short* __restrict__ q,
                                               const unsigned short* __restrict__ k,
                                               float* __restrict__ qn, float* __restrict__ kn){
  int i = blockIdx.x * blockDim.x + threadIdx.x;  // [0, 65536)
  const uint4* qr = (const uint4*)(q + (size_t)i * HD);
  const uint4* kr = (const uint4*)(k + (size_t)i * HD);
  float sq = 0.f, sk = 0.f;
  #pragma unroll
  for (int t = 0; t < 8; t++){
    uint4 uq = qr[t], uk = kr[t];
    unsigned aq[4] = {uq.x, uq.y, uq.z, uq.w};
    unsigned ak[4] = {uk.x, uk.y, uk.z, uk.w};
    #pragma unroll
    for (int j = 0; j < 4; j++){
      float f0 = bf2f((unsigned short)(aq[j] & 0xffff));
      float f1 = bf2f((unsigned short)(aq[j] >> 16));
      sq += f0*f0 + f1*f1;
      float g0 = bf2f((unsigned short)(ak[j] & 0xffff));
      float g1 = bf2f((unsigned short)(ak[j] >> 16));
      sk += g0*g0 + g1*g1;
    }
  }
  qn[i] = sq; kn[i] = sk;
}

// ---------------- GEMM1: x @ w_qkv + b -> scatter q,k (bf16), v (f16) [BH][L][D] ----------------

__global__ __launch_bounds__(256) void k_gemm_qkv(
    const unsigned short* __restrict__ A,    // [4096][1024] bf16
    const unsigned short* __restrict__ BT,   // [3072][1024] bf16
    const float* __restrict__ bias,          // [3072]
    unsigned short* __restrict__ qo, unsigned short* __restrict__ ko,
    unsigned short* __restrict__ vo)
{
  __shared__ __align__(16) unsigned short As[64][32];
  __shared__ __align__(16) unsigned short Bs[64][32];
  const int K = EMBED;
  int m0 = blockIdx.x * 64, n0 = blockIdx.y * 64;
  int tid = threadIdx.x, lane = tid & 63, wave = tid >> 6;
  int wm = wave >> 1, wn = wave & 1;
  int l16 = lane & 15, quad = lane >> 4;
  f32x4 acc[2][2] = {};
  int lr = tid >> 2, lc = (tid & 3) * 8;
  for (int k0 = 0; k0 < K; k0 += 32){
    *(uint4*)&As[lr][lc] = *(const uint4*)&A[(size_t)(m0 + lr) * K + k0 + lc];
    *(uint4*)&Bs[lr][lc] = *(const uint4*)&BT[(size_t)(n0 + lr) * K + k0 + lc];
    __syncthreads();
    bf16x8 af[2], bfr[2];
    #pragma unroll
    for (int mi = 0; mi < 2; mi++) af[mi]  = *(const bf16x8*)&As[wm*32 + mi*16 + l16][quad*8];
    #pragma unroll
    for (int ni = 0; ni < 2; ni++) bfr[ni] = *(const bf16x8*)&Bs[wn*32 + ni*16 + l16][quad*8];
    #pragma unroll
    for (int mi = 0; mi < 2; mi++)
      #pragma unroll
      for (int ni = 0; ni < 2; ni++)
        acc[mi][ni] = __builtin_amdgcn_mfma_f32_16x16x32_bf16(af[mi], bfr[ni], acc[mi][ni], 0, 0, 0);
    __syncthreads();
  }
  #pragma unroll
  for (int mi = 0; mi < 2; mi++)
    #pragma unroll
    for (int ni = 0; ni < 2; ni++)
      #pragma unroll
      for (int rr = 0; rr < 4; rr++){
        int row = m0 + wm*32 + mi*16 + quad*4 + rr;
        int col = n0 + wn*32 + ni*16 + l16;
        float val = acc[mi][ni][rr] + bias[col];
        int b = row >> 11, l = row & 2047;
        int which = col >> 10, e = col & 1023, h = e >> 6, d = e & 63;
        unsigned short* dst = which == 0 ? qo : (which == 1 ? ko : vo);
        unsigned short bits = (which == 2) ? f2h(val) : f2bf(val);
        dst[(((size_t)(b*NH + h))*SEQ + l)*HD + d] = bits;
      }
}

// ---------------- attention (S^T formulation, register-resident P) ----------------

__global__ __launch_bounds__(256) void k_attn(
    const unsigned short* __restrict__ qg,   // [BH][L][D] bf16
    const unsigned short* __restrict__ kg,   // [BH][L][D] bf16
    const unsigned short* __restrict__ vtg,  // [BH][D][L] f16
    const float* __restrict__ qn,
    const float* __restrict__ kn,
    unsigned short* __restrict__ attn_out)   // [ROWS][EMBED] bf16
{
  int bh = blockIdx.y; int b = bh >> 4, h = bh & 15;
  int tid = threadIdx.x, lane = tid & 63, wave = tid >> 6;
  int l16 = lane & 15, quad = lane >> 4;
  int p = blockIdx.x * 4 + wave;           // pair id in [0,64)
  const unsigned short* qbase = qg  + (size_t)bh * SEQ * HD;
  const unsigned short* kbase = kg  + (size_t)bh * SEQ * HD;
  const _Float16*       vtb   = (const _Float16*)vtg + (size_t)bh * HD * SEQ;
  const float* knb = kn + (size_t)bh * SEQ;

  #pragma unroll
  for (int side = 0; side < 2; side++){
    int t = side ? (127 - p) : p;          // tiles {p, 127-p} -> uniform work per wave
    int q0 = t * 16;

    // Q fragment: B-operand of S^T MFMA — lane holds row m=l16, 8 contiguous d
    bf16x8 aq[2];
    #pragma unroll
    for (int s = 0; s < 2; s++)
      aq[s] = *(const bf16x8*)&qbase[(size_t)(q0 + l16)*HD + s*32 + quad*8];
    float qn_m = qn[(size_t)bh*SEQ + q0 + l16];

    float m_run = -1e30f, l_run = 0.f;     // per-lane: softmax row m = l16
    f32x4 oacc[4] = {};

    int jmax = q0 + 16;
    for (int j0 = 0; j0 < jmax; j0 += 32){
      // S^T tiles: D = K-frag(A) x Q-frag(B); C-layout: col=m=l16, row=j=quad*4+rr
      f32x4 st[2] = {};
      #pragma unroll
      for (int tile = 0; tile < 2; tile++)
        #pragma unroll
        for (int sk = 0; sk < 2; sk++){
          bf16x8 ak = *(const bf16x8*)&kbase[(size_t)(j0 + tile*16 + l16)*HD + sk*32 + quad*8];
          st[tile] = __builtin_amdgcn_mfma_f32_16x16x32_bf16(ak, aq[sk], st[tile], 0, 0, 0);
        }
      // k-norms for this lane's 4 j rows (contiguous -> float4)
      float4 kn_a = *(const float4*)&knb[j0 + quad*4];
      float4 kn_b = *(const float4*)&knb[j0 + 16 + quad*4];
      float kn_j[2][4] = {{kn_a.x, kn_a.y, kn_a.z, kn_a.w}, {kn_b.x, kn_b.y, kn_b.z, kn_b.w}};

      int mg = q0 + l16;
      float sc[2][4];
      #pragma unroll
      for (int tile = 0; tile < 2; tile++)
        #pragma unroll
        for (int rr = 0; rr < 4; rr++){
          int jg = j0 + tile*16 + quad*4 + rr;
          float dot = st[tile][rr];
          float den = fmaxf(qn_m + kn_j[tile][rr] - 2.0f*dot, 0.0f) + 1e-6f;
          float v = dot * dot * __builtin_amdgcn_rcpf(den);
          sc[tile][rr] = (jg <= mg) ? v : -1e30f;
        }
      // row max: in-lane over 8, then across quads (xor 16, 32)
      float mx = fmaxf(fmaxf(fmaxf(sc[0][0], sc[0][1]), fmaxf(sc[0][2], sc[0][3])),
                       fmaxf(fmaxf(sc[1][0], sc[1][1]), fmaxf(sc[1][2], sc[1][3])));
      mx = fmaxf(mx, __shfl_xor(mx, 16));
      mx = fmaxf(mx, __shfl_xor(mx, 32));
      float mnew = fmaxf(m_run, mx);
      float alpha = __expf(m_run - mnew);
      m_run = mnew;

      float ps = 0.f;
      #pragma unroll
      for (int tile = 0; tile < 2; tile++)
        #pragma unroll
        for (int rr = 0; rr < 4; rr++){
          float e = __expf(sc[tile][rr] - mnew);
          sc[tile][rr] = e; ps += e;
        }
      ps += __shfl_xor(ps, 16);
      ps += __shfl_xor(ps, 32);
      l_run = l_run * alpha + ps;

      // broadcast alpha for oacc rows m = quad*4+rr
      float alpha_r[4];
      #pragma unroll
      for (int rr = 0; rr < 4; rr++) alpha_r[rr] = __shfl(alpha, quad*4 + rr);
      #pragma unroll
      for (int g = 0; g < 4; g++)
        #pragma unroll
        for (int rr = 0; rr < 4; rr++) oacc[g][rr] *= alpha_r[rr];

      // PV: P's S^T C-layout IS the 16x16x16 A-layout (lane m=l16, k=quad*4+i)
      #pragma unroll
      for (int tile = 0; tile < 2; tile++){
        f16x4 ap;
        #pragma unroll
        for (int rr = 0; rr < 4; rr++) ap[rr] = (_Float16)sc[tile][rr];
        #pragma unroll
        for (int g = 0; g < 4; g++){
          f16x4 bv = *(const f16x4*)&vtb[(size_t)(g*16 + l16)*SEQ + j0 + tile*16 + quad*4];
          oacc[g] = __builtin_amdgcn_mfma_f32_16x16x16f16(ap, bv, oacc[g], 0, 0, 0);
        }
      }
    }

    // epilogue: O C-layout rows m = quad*4+rr; fetch l for those rows
    float linv[4];
    #pragma unroll
    for (int rr = 0; rr < 4; rr++)
      linv[rr] = __builtin_amdgcn_rcpf(__shfl(l_run, quad*4 + rr));
    #pragma unroll
    for (int g = 0; g < 4; g++)
      #pragma unroll
      for (int rr = 0; rr < 4; rr++){
        int lq = q0 + quad*4 + rr;
        int arow = b*SEQ + lq;
        int acol = h*HD + g*16 + l16;
        attn_out[(size_t)arow*EMBED + acol] = f2bf(oacc[g][rr] * linv[rr]);
      }
  }
}

// ---------------- GEMM2: attn_out @ w_out + b_out -> fp32 ----------------

__global__ __launch_bounds__(256) void k_gemm_out(
    const unsigned short* __restrict__ A,    // [4096][1024] bf16
    const unsigned short* __restrict__ BT,   // [1024][1024] bf16
    const float* __restrict__ bias,          // [1024]
    float* __restrict__ out)
{
  __shared__ __align__(16) unsigned short As[64][32];
  __shared__ __align__(16) unsigned short Bs[64][32];
  const int K = EMBED;
  int m0 = blockIdx.x * 64, n0 = blockIdx.y * 64;
  int tid = threadIdx.x, lane = tid & 63, wave = tid >> 6;
  int wm = wave >> 1, wn = wave & 1;
  int l16 = lane & 15, quad = lane >> 4;
  f32x4 acc[2][2] = {};
  int lr = tid >> 2, lc = (tid & 3) * 8;
  for (int k0 = 0; k0 < K; k0 += 32){
    *(uint4*)&As[lr][lc] = *(const uint4*)&A[(size_t)(m0 + lr) * K + k0 + lc];
    *(uint4*)&Bs[lr][lc] = *(const uint4*)&BT[(size_t)(n0 + lr) * K + k0 + lc];
    __syncthreads();
    bf16x8 af[2], bfr[2];
    #pragma unroll
    for (int mi = 0; mi < 2; mi++) af[mi]  = *(const bf16x8*)&As[wm*32 + mi*16 + l16][quad*8];
    #pragma unroll
    for (int ni = 0; ni < 2; ni++) bfr[ni] = *(const bf16x8*)&Bs[wn*32 + ni*16 + l16][quad*8];
    #pragma unroll
    for (int mi = 0; mi < 2; mi++)
      #pragma unroll
      for (int ni = 0; ni < 2; ni++)
        acc[mi][ni] = __builtin_amdgcn_mfma_f32_16x16x32_bf16(af[mi], bfr[ni], acc[mi][ni], 0, 0, 0);
    __syncthreads();
  }
  #pragma unroll
  for (int mi = 0; mi < 2; mi++)
    #pragma unroll
    for (int ni = 0; ni < 2; ni++)
      #pragma unroll
      for (int rr = 0; rr < 4; rr++){
        int row = m0 + wm*32 + mi*16 + quad*4 + rr;
        int col = n0 + wn*32 + ni*16 + l16;
        out[(size_t)row*EMBED + col] = acc[mi][ni][rr] + bias[col];
      }
}

// ---------------- launch ----------------

extern "C" void kernel_launch(void* const* d_in, const int* in_sizes, int n_in,
                              void* d_out, int out_size, void* d_ws, size_t ws_size,
                              hipStream_t stream) {
  const float* x     = (const float*)d_in[0];
  const float* w_qkv = (const float*)d_in[1];
  const float* b_qkv = (const float*)d_in[2];
  const float* w_out = (const float*)d_in[3];
  const float* b_out = (const float*)d_in[4];
  float* out = (float*)d_out;

  char* ws = (char*)d_ws;
  size_t off = 0;
  auto alloc = [&](size_t bytes) -> void* {
    void* p = ws + off; off += (bytes + 255) & ~(size_t)255; return p;
  };
  unsigned short* xb    = (unsigned short*)alloc((size_t)ROWS * EMBED * 2);      // 8 MB
  unsigned short* wqkvT = (unsigned short*)alloc((size_t)3 * EMBED * EMBED * 2); // 6 MB
  unsigned short* woutT = (unsigned short*)alloc((size_t)EMBED * EMBED * 2);     // 2 MB
  unsigned short* qb    = (unsigned short*)alloc((size_t)ROWS * EMBED * 2);
  unsigned short* kb    = (unsigned short*)alloc((size_t)ROWS * EMBED * 2);
  unsigned short* vb    = (unsigned short*)alloc((size_t)ROWS * EMBED * 2);      // f16 bits
  unsigned short* vTb   = (unsigned short*)alloc((size_t)ROWS * EMBED * 2);      // f16 bits
  float* qn = (float*)alloc((size_t)BHD * SEQ * 4);
  float* kn = (float*)alloc((size_t)BHD * SEQ * 4);
  unsigned short* attnb = xb;  // xb is dead after GEMM1 — alias to save workspace

  k_conv<<<dim3((ROWS*EMBED/4 + 255)/256), dim3(256), 0, stream>>>(x, xb, ROWS*EMBED/4);
  k_tr_f2b<<<dim3(3*EMBED/32, EMBED/32), dim3(32, 8), 0, stream>>>(w_qkv, wqkvT, EMBED, 3*EMBED);
  k_tr_f2b<<<dim3(EMBED/32, EMBED/32), dim3(32, 8), 0, stream>>>(w_out, woutT, EMBED, EMBED);
  k_gemm_qkv<<<dim3(ROWS/64, 3*EMBED/64), dim3(256), 0, stream>>>(xb, wqkvT, b_qkv, qb, kb, vb);
  k_norms<<<dim3(BHD*SEQ/256), dim3(256), 0, stream>>>(qb, kb, qn, kn);
  k_tr_b2b<<<dim3(HD/32, SEQ/32, BHD), dim3(32, 8), 0, stream>>>(vb, vTb, SEQ, HD);
  k_attn<<<dim3(16, BHD), dim3(256), 0, stream>>>(qb, kb, vTb, qn, kn, attnb);
  k_gemm_out<<<dim3(ROWS/64, EMBED/64), dim3(256), 0, stream>>>(attnb, woutT, b_out, out);
}

// Round 3
// 335.672 us; speedup vs baseline: 1.2112x; 1.0538x over previous
//
#include <hip/hip_runtime.h>

#define EMBED 1024
#define NH 16
#define HD 64
#define SEQ 2048
#define BATCH 2
#define ROWS (BATCH*SEQ)   // 4096
#define BHD (BATCH*NH)     // 32

typedef __bf16 bf16x8 __attribute__((ext_vector_type(8)));
typedef _Float16 f16x4 __attribute__((ext_vector_type(4)));
typedef float f32x4 __attribute__((ext_vector_type(4)));

__device__ __forceinline__ unsigned short f2bf(float f){
  union { float f; unsigned u; } v; v.f = f;
  unsigned r = v.u + 0x7fffu + ((v.u >> 16) & 1u);
  return (unsigned short)(r >> 16);
}
__device__ __forceinline__ float bf2f(unsigned short s){
  union { unsigned u; float f; } v; v.u = ((unsigned)s) << 16; return v.f;
}
__device__ __forceinline__ unsigned short f2h(float f){
  union { _Float16 h; unsigned short u; } v; v.h = (_Float16)f; return v.u;
}

// async global->LDS, 16B per lane; lds ptr must be wave-uniform base (lane*16 implicit)
typedef __attribute__((address_space(1))) unsigned int as1_t;
typedef __attribute__((address_space(3))) unsigned int as3_t;
__device__ __forceinline__ void async_ld16(void* gp, void* lp){
  __builtin_amdgcn_global_load_lds((as1_t*)gp, (as3_t*)lp, 16, 0, 0);
}

// ---------------- prep kernels ----------------

__global__ __launch_bounds__(256) void k_conv(const float* __restrict__ x,
                                              unsigned short* __restrict__ xb, int n4){
  int i = blockIdx.x * blockDim.x + threadIdx.x;
  if (i < n4){
    float4 f = ((const float4*)x)[i];
    ushort4 o;
    o.x = f2bf(f.x); o.y = f2bf(f.y); o.z = f2bf(f.z); o.w = f2bf(f.w);
    ((ushort4*)xb)[i] = o;
  }
}

// in[R][C] fp32 -> out[C][R] bf16
__global__ __launch_bounds__(256) void k_tr_f2b(const float* __restrict__ in,
                                                unsigned short* __restrict__ out, int R, int C){
  __shared__ float t[32][33];
  int c0 = blockIdx.x * 32, r0 = blockIdx.y * 32;
  int tx = threadIdx.x, ty = threadIdx.y;
  #pragma unroll
  for (int i = 0; i < 4; i++){ int r = ty + i*8; t[r][tx] = in[(size_t)(r0+r)*C + c0 + tx]; }
  __syncthreads();
  #pragma unroll
  for (int i = 0; i < 4; i++){ int rr = ty + i*8; out[(size_t)(c0+rr)*R + r0 + tx] = f2bf(t[tx][rr]); }
}

// batched 16-bit transpose: in[batch][R][C] -> out[batch][C][R]
__global__ __launch_bounds__(256) void k_tr_b2b(const unsigned short* __restrict__ in,
                                                unsigned short* __restrict__ out, int R, int C){
  in  += (size_t)blockIdx.z * R * C;
  out += (size_t)blockIdx.z * R * C;
  __shared__ unsigned short t[32][33];
  int c0 = blockIdx.x * 32, r0 = blockIdx.y * 32;
  int tx = threadIdx.x, ty = threadIdx.y;
  #pragma unroll
  for (int i = 0; i < 4; i++){ int r = ty + i*8; t[r][tx] = in[(size_t)(r0+r)*C + c0 + tx]; }
  __syncthreads();
  #pragma unroll
  for (int i = 0; i < 4; i++){ int rr = ty + i*8; out[(size_t)(c0+rr)*R + r0 + tx] = t[tx][rr]; }
}

// qn/kn from bf16-rounded q,k (keeps denominator = |q~ - k~|^2 >= 0)
__global__ __launch_bounds__(256) void k_norms(const unsigned short* __restrict__ q,
                                               const unsigned short* __restrict__ k,
                                               float* __restrict__ qn, float* __restrict__ kn){
  int i = blockIdx.x * blockDim.x + threadIdx.x;  // [0, 65536)
  const uint4* qr = (const uint4*)(q + (size_t)i * HD);
  const uint4* kr = (const uint4*)(k + (size_t)i * HD);
  float sq = 0.f, sk = 0.f;
  #pragma unroll
  for (int t = 0; t < 8; t++){
    uint4 uq = qr[t], uk = kr[t];
    unsigned aq[4] = {uq.x, uq.y, uq.z, uq.w};
    unsigned ak[4] = {uk.x, uk.y, uk.z, uk.w};
    #pragma unroll
    for (int j = 0; j < 4; j++){
      float f0 = bf2f((unsigned short)(aq[j] & 0xffff));
      float f1 = bf2f((unsigned short)(aq[j] >> 16));
      sq += f0*f0 + f1*f1;
      float g0 = bf2f((unsigned short)(ak[j] & 0xffff));
      float g1 = bf2f((unsigned short)(ak[j] >> 16));
      sk += g0*g0 + g1*g1;
    }
  }
  qn[i] = sq; kn[i] = sk;
}

// ---------------- GEMM1: 128x128 tile, global_load_lds staging ----------------
// x @ w_qkv + b -> scatter q,k (bf16), v (f16) [BH][L][D]

__global__ __launch_bounds__(256) void k_gemm_qkv(
    const unsigned short* __restrict__ A,    // [4096][1024] bf16
    const unsigned short* __restrict__ BT,   // [3072][1024] bf16
    const float* __restrict__ bias,          // [3072]
    unsigned short* __restrict__ qo, unsigned short* __restrict__ ko,
    unsigned short* __restrict__ vo)
{
  __shared__ __align__(16) unsigned short As[128*32];
  __shared__ __align__(16) unsigned short Bs[128*32];
  const int K = EMBED;
  int m0 = blockIdx.x * 128, n0 = blockIdx.y * 128;
  int tid = threadIdx.x, lane = tid & 63, wave = tid >> 6;
  int wm = wave >> 1, wn = wave & 1;
  int l16 = lane & 15, quad = lane >> 4;
  f32x4 acc[4][4] = {};
  // staging map: chunk = it*256 + wave*64 + lane; row=chunk>>2, cc=chunk&3
  int c0i = wave*64 + lane, c1i = 256 + wave*64 + lane;
  int r0 = c0i >> 2, cc0 = (c0i & 3) * 8;
  int r1 = c1i >> 2, cc1 = (c1i & 3) * 8;
  unsigned short* lA0 = &As[(wave*64)*8];        // wave-uniform
  unsigned short* lA1 = &As[(256 + wave*64)*8];
  unsigned short* lB0 = &Bs[(wave*64)*8];
  unsigned short* lB1 = &Bs[(256 + wave*64)*8];
  for (int k0 = 0; k0 < K; k0 += 32){
    async_ld16((void*)&A [(size_t)(m0 + r0)*K + k0 + cc0], (void*)lA0);
    async_ld16((void*)&A [(size_t)(m0 + r1)*K + k0 + cc1], (void*)lA1);
    async_ld16((void*)&BT[(size_t)(n0 + r0)*K + k0 + cc0], (void*)lB0);
    async_ld16((void*)&BT[(size_t)(n0 + r1)*K + k0 + cc1], (void*)lB1);
    __syncthreads();
    bf16x8 af[4], bfr[4];
    #pragma unroll
    for (int mi = 0; mi < 4; mi++) af[mi]  = *(const bf16x8*)&As[(wm*64 + mi*16 + l16)*32 + quad*8];
    #pragma unroll
    for (int ni = 0; ni < 4; ni++) bfr[ni] = *(const bf16x8*)&Bs[(wn*64 + ni*16 + l16)*32 + quad*8];
    #pragma unroll
    for (int mi = 0; mi < 4; mi++)
      #pragma unroll
      for (int ni = 0; ni < 4; ni++)
        acc[mi][ni] = __builtin_amdgcn_mfma_f32_16x16x32_bf16(af[mi], bfr[ni], acc[mi][ni], 0, 0, 0);
    __syncthreads();
  }
  #pragma unroll
  for (int mi = 0; mi < 4; mi++)
    #pragma unroll
    for (int ni = 0; ni < 4; ni++)
      #pragma unroll
      for (int rr = 0; rr < 4; rr++){
        int row = m0 + wm*64 + mi*16 + quad*4 + rr;
        int col = n0 + wn*64 + ni*16 + l16;
        float val = acc[mi][ni][rr] + bias[col];
        int b = row >> 11, l = row & 2047;
        int which = col >> 10, e = col & 1023, h = e >> 6, d = e & 63;
        unsigned short* dst = which == 0 ? qo : (which == 1 ? ko : vo);
        unsigned short bits = (which == 2) ? f2h(val) : f2bf(val);
        dst[(((size_t)(b*NH + h))*SEQ + l)*HD + d] = bits;
      }
}

// ---------------- attention (S^T form, register-resident P, reg double-buffer prefetch) ----------------

__global__ __launch_bounds__(256) void k_attn(
    const unsigned short* __restrict__ qg,   // [BH][L][D] bf16
    const unsigned short* __restrict__ kg,   // [BH][L][D] bf16
    const unsigned short* __restrict__ vtg,  // [BH][D][L] f16
    const float* __restrict__ qn,
    const float* __restrict__ kn,
    unsigned short* __restrict__ attn_out)   // [ROWS][EMBED] bf16
{
  int bh = blockIdx.y; int b = bh >> 4, h = bh & 15;
  int tid = threadIdx.x, lane = tid & 63, wave = tid >> 6;
  int l16 = lane & 15, quad = lane >> 4;
  int p = blockIdx.x * 4 + wave;           // pair id in [0,64)
  const unsigned short* qbase = qg  + (size_t)bh * SEQ * HD;
  const unsigned short* kbase = kg  + (size_t)bh * SEQ * HD;
  const _Float16*       vtb   = (const _Float16*)vtg + (size_t)bh * HD * SEQ;
  const float* knb = kn + (size_t)bh * SEQ;

  auto load_blk = [&](int J, bf16x8 kd[2][2], f16x4 vd[4][2], float4 nd[2]){
    #pragma unroll
    for (int tile = 0; tile < 2; tile++)
      #pragma unroll
      for (int sk = 0; sk < 2; sk++)
        kd[tile][sk] = *(const bf16x8*)&kbase[(size_t)(J + tile*16 + l16)*HD + sk*32 + quad*8];
    #pragma unroll
    for (int g = 0; g < 4; g++)
      #pragma unroll
      for (int tile = 0; tile < 2; tile++)
        vd[g][tile] = *(const f16x4*)&vtb[(size_t)(g*16 + l16)*SEQ + J + tile*16 + quad*4];
    nd[0] = *(const float4*)&knb[J + quad*4];
    nd[1] = *(const float4*)&knb[J + 16 + quad*4];
  };

  #pragma unroll
  for (int side = 0; side < 2; side++){
    int t = side ? (127 - p) : p;          // tiles {p, 127-p} -> uniform work per wave
    int q0 = t * 16;

    bf16x8 aq[2];
    #pragma unroll
    for (int s = 0; s < 2; s++)
      aq[s] = *(const bf16x8*)&qbase[(size_t)(q0 + l16)*HD + s*32 + quad*8];
    float qn_m = qn[(size_t)bh*SEQ + q0 + l16];

    float m_run = -1e30f, l_run = 0.f;     // per-lane: softmax row m = l16
    f32x4 oacc[4] = {};

    int jmax = q0 + 16;
    bf16x8 kc[2][2]; f16x4 vc[4][2]; float4 nc[2];
    load_blk(0, kc, vc, nc);

    for (int j0 = 0; j0 < jmax; j0 += 32){
      // ---- prefetch next block into alt registers (waitcnt lands after compute) ----
      int jn = (j0 + 32 < jmax) ? j0 + 32 : j0;
      bf16x8 kx[2][2]; f16x4 vx[4][2]; float4 nx[2];
      load_blk(jn, kx, vx, nx);

      // ---- S^T: D = K(A) x Q(B); C-layout: col=m=l16, row=j=quad*4+rr ----
      f32x4 st[2] = {};
      #pragma unroll
      for (int tile = 0; tile < 2; tile++)
        #pragma unroll
        for (int sk = 0; sk < 2; sk++)
          st[tile] = __builtin_amdgcn_mfma_f32_16x16x32_bf16(kc[tile][sk], aq[sk], st[tile], 0, 0, 0);

      float kn_j[2][4] = {{nc[0].x, nc[0].y, nc[0].z, nc[0].w},
                          {nc[1].x, nc[1].y, nc[1].z, nc[1].w}};
      int mg = q0 + l16;
      float sc[2][4];
      if (j0 + 32 > q0){  // wave-uniform: block touches the diagonal -> mask
        #pragma unroll
        for (int tile = 0; tile < 2; tile++)
          #pragma unroll
          for (int rr = 0; rr < 4; rr++){
            int jg = j0 + tile*16 + quad*4 + rr;
            float dot = st[tile][rr];
            float den = fmaxf(qn_m + kn_j[tile][rr] - 2.0f*dot, 0.0f) + 1e-6f;
            float v = dot * dot * __builtin_amdgcn_rcpf(den);
            sc[tile][rr] = (jg <= mg) ? v : -1e30f;
          }
      } else {
        #pragma unroll
        for (int tile = 0; tile < 2; tile++)
          #pragma unroll
          for (int rr = 0; rr < 4; rr++){
            float dot = st[tile][rr];
            float den = fmaxf(qn_m + kn_j[tile][rr] - 2.0f*dot, 0.0f) + 1e-6f;
            sc[tile][rr] = dot * dot * __builtin_amdgcn_rcpf(den);
          }
      }
      // row max: in-lane over 8, then across quads (xor 16, 32)
      float mx = fmaxf(fmaxf(fmaxf(sc[0][0], sc[0][1]), fmaxf(sc[0][2], sc[0][3])),
                       fmaxf(fmaxf(sc[1][0], sc[1][1]), fmaxf(sc[1][2], sc[1][3])));
      mx = fmaxf(mx, __shfl_xor(mx, 16));
      mx = fmaxf(mx, __shfl_xor(mx, 32));
      float mnew = fmaxf(m_run, mx);
      float alpha = __expf(m_run - mnew);
      m_run = mnew;

      float ps = 0.f;
      #pragma unroll
      for (int tile = 0; tile < 2; tile++)
        #pragma unroll
        for (int rr = 0; rr < 4; rr++){
          float e = __expf(sc[tile][rr] - mnew);
          sc[tile][rr] = e; ps += e;
        }
      ps += __shfl_xor(ps, 16);
      ps += __shfl_xor(ps, 32);
      l_run = l_run * alpha + ps;

      float alpha_r[4];
      #pragma unroll
      for (int rr = 0; rr < 4; rr++) alpha_r[rr] = __shfl(alpha, quad*4 + rr);
      #pragma unroll
      for (int g = 0; g < 4; g++)
        #pragma unroll
        for (int rr = 0; rr < 4; rr++) oacc[g][rr] *= alpha_r[rr];

      // PV: P's S^T C-layout IS the 16x16x16 A-layout
      #pragma unroll
      for (int tile = 0; tile < 2; tile++){
        f16x4 ap;
        #pragma unroll
        for (int rr = 0; rr < 4; rr++) ap[rr] = (_Float16)sc[tile][rr];
        #pragma unroll
        for (int g = 0; g < 4; g++)
          oacc[g] = __builtin_amdgcn_mfma_f32_16x16x16f16(ap, vc[g][tile], oacc[g], 0, 0, 0);
      }

      // ---- rotate buffers (compiler waits vmcnt here, after the compute) ----
      #pragma unroll
      for (int tile = 0; tile < 2; tile++)
        #pragma unroll
        for (int sk = 0; sk < 2; sk++) kc[tile][sk] = kx[tile][sk];
      #pragma unroll
      for (int g = 0; g < 4; g++)
        #pragma unroll
        for (int tile = 0; tile < 2; tile++) vc[g][tile] = vx[g][tile];
      nc[0] = nx[0]; nc[1] = nx[1];
    }

    float linv[4];
    #pragma unroll
    for (int rr = 0; rr < 4; rr++)
      linv[rr] = __builtin_amdgcn_rcpf(__shfl(l_run, quad*4 + rr));
    #pragma unroll
    for (int g = 0; g < 4; g++)
      #pragma unroll
      for (int rr = 0; rr < 4; rr++){
        int lq = q0 + quad*4 + rr;
        int arow = b*SEQ + lq;
        int acol = h*HD + g*16 + l16;
        attn_out[(size_t)arow*EMBED + acol] = f2bf(oacc[g][rr] * linv[rr]);
      }
  }
}

// ---------------- GEMM2: 128x128 tile, attn_out @ w_out + b_out -> fp32 ----------------

__global__ __launch_bounds__(256) void k_gemm_out(
    const unsigned short* __restrict__ A,    // [4096][1024] bf16
    const unsigned short* __restrict__ BT,   // [1024][1024] bf16
    const float* __restrict__ bias,          // [1024]
    float* __restrict__ out)
{
  __shared__ __align__(16) unsigned short As[128*32];
  __shared__ __align__(16) unsigned short Bs[128*32];
  const int K = EMBED;
  int m0 = blockIdx.x * 128, n0 = blockIdx.y * 128;
  int tid = threadIdx.x, lane = tid & 63, wave = tid >> 6;
  int wm = wave >> 1, wn = wave & 1;
  int l16 = lane & 15, quad = lane >> 4;
  f32x4 acc[4][4] = {};
  int c0i = wave*64 + lane, c1i = 256 + wave*64 + lane;
  int r0 = c0i >> 2, cc0 = (c0i & 3) * 8;
  int r1 = c1i >> 2, cc1 = (c1i & 3) * 8;
  unsigned short* lA0 = &As[(wave*64)*8];
  unsigned short* lA1 = &As[(256 + wave*64)*8];
  unsigned short* lB0 = &Bs[(wave*64)*8];
  unsigned short* lB1 = &Bs[(256 + wave*64)*8];
  for (int k0 = 0; k0 < K; k0 += 32){
    async_ld16((void*)&A [(size_t)(m0 + r0)*K + k0 + cc0], (void*)lA0);
    async_ld16((void*)&A [(size_t)(m0 + r1)*K + k0 + cc1], (void*)lA1);
    async_ld16((void*)&BT[(size_t)(n0 + r0)*K + k0 + cc0], (void*)lB0);
    async_ld16((void*)&BT[(size_t)(n0 + r1)*K + k0 + cc1], (void*)lB1);
    __syncthreads();
    bf16x8 af[4], bfr[4];
    #pragma unroll
    for (int mi = 0; mi < 4; mi++) af[mi]  = *(const bf16x8*)&As[(wm*64 + mi*16 + l16)*32 + quad*8];
    #pragma unroll
    for (int ni = 0; ni < 4; ni++) bfr[ni] = *(const bf16x8*)&Bs[(wn*64 + ni*16 + l16)*32 + quad*8];
    #pragma unroll
    for (int mi = 0; mi < 4; mi++)
      #pragma unroll
      for (int ni = 0; ni < 4; ni++)
        acc[mi][ni] = __builtin_amdgcn_mfma_f32_16x16x32_bf16(af[mi], bfr[ni], acc[mi][ni], 0, 0, 0);
    __syncthreads();
  }
  #pragma unroll
  for (int mi = 0; mi < 4; mi++)
    #pragma unroll
    for (int ni = 0; ni < 4; ni++)
      #pragma unroll
      for (int rr = 0; rr < 4; rr++){
        int row = m0 + wm*64 + mi*16 + quad*4 + rr;
        int col = n0 + wn*64 + ni*16 + l16;
        out[(size_t)row*EMBED + col] = acc[mi][ni][rr] + bias[col];
      }
}

// ---------------- launch ----------------

extern "C" void kernel_launch(void* const* d_in, const int* in_sizes, int n_in,
                              void* d_out, int out_size, void* d_ws, size_t ws_size,
                              hipStream_t stream) {
  const float* x     = (const float*)d_in[0];
  const float* w_qkv = (const float*)d_in[1];
  const float* b_qkv = (const float*)d_in[2];
  const float* w_out = (const float*)d_in[3];
  const float* b_out = (const float*)d_in[4];
  float* out = (float*)d_out;

  char* ws = (char*)d_ws;
  size_t off = 0;
  auto alloc = [&](size_t bytes) -> void* {
    void* p = ws + off; off += (bytes + 255) & ~(size_t)255; return p;
  };
  unsigned short* xb    = (unsigned short*)alloc((size_t)ROWS * EMBED * 2);      // 8 MB
  unsigned short* wqkvT = (unsigned short*)alloc((size_t)3 * EMBED * EMBED * 2); // 6 MB
  unsigned short* woutT = (unsigned short*)alloc((size_t)EMBED * EMBED * 2);     // 2 MB
  unsigned short* qb    = (unsigned short*)alloc((size_t)ROWS * EMBED * 2);
  unsigned short* kb    = (unsigned short*)alloc((size_t)ROWS * EMBED * 2);
  unsigned short* vb    = (unsigned short*)alloc((size_t)ROWS * EMBED * 2);      // f16 bits
  unsigned short* vTb   = (unsigned short*)alloc((size_t)ROWS * EMBED * 2);      // f16 bits
  float* qn = (float*)alloc((size_t)BHD * SEQ * 4);
  float* kn = (float*)alloc((size_t)BHD * SEQ * 4);
  unsigned short* attnb = xb;  // xb is dead after GEMM1 — alias to save workspace

  k_conv<<<dim3((ROWS*EMBED/4 + 255)/256), dim3(256), 0, stream>>>(x, xb, ROWS*EMBED/4);
  k_tr_f2b<<<dim3(3*EMBED/32, EMBED/32), dim3(32, 8), 0, stream>>>(w_qkv, wqkvT, EMBED, 3*EMBED);
  k_tr_f2b<<<dim3(EMBED/32, EMBED/32), dim3(32, 8), 0, stream>>>(w_out, woutT, EMBED, EMBED);
  k_gemm_qkv<<<dim3(ROWS/128, 3*EMBED/128), dim3(256), 0, stream>>>(xb, wqkvT, b_qkv, qb, kb, vb);
  k_norms<<<dim3(BHD*SEQ/256), dim3(256), 0, stream>>>(qb, kb, qn, kn);
  k_tr_b2b<<<dim3(HD/32, SEQ/32, BHD), dim3(32, 8), 0, stream>>>(vb, vTb, SEQ, HD);
  k_attn<<<dim3(16, BHD), dim3(256), 0, stream>>>(qb, kb, vTb, qn, kn, attnb);
  k_gemm_out<<<dim3(ROWS/128, EMBED/128), dim3(256), 0, stream>>>(attnb, woutT, b_out, out);
}